// Round 1
// 131.297 us; speedup vs baseline: 1.1071x; 1.1071x over previous
//
#include <hip/hip_runtime.h>
#include <hip/hip_bf16.h>

#define B_BATCH 512
#define NPB     500
#define DIM     128
#define VOCAB   50000
#define MAXD    40
#define NPREP   512
#define NGEMM   ((VOCAB + 63) / 64)   // 782

typedef short bf16x8 __attribute__((ext_vector_type(8)));
typedef float f32x4  __attribute__((ext_vector_type(4)));

__device__ __forceinline__ unsigned short f2bf(float x) {
    unsigned u = __float_as_uint(x);
    return (unsigned short)((u + 0x7fffu + ((u >> 16) & 1u)) >> 16);   // RTNE
}

// ---------- fused prep (blocks 0..511) + MFMA gemm (blocks 512..1293) ----------
__global__ __launch_bounds__(256) void prep_gemm(const int* __restrict__ tokens,
                                                 const int* __restrict__ parent,
                                                 const int* __restrict__ depth,
                                                 const float* __restrict__ emb,
                                                 const float* __restrict__ Wc,
                                                 const float* __restrict__ bc,
                                                 int* __restrict__ tokD,
                                                 unsigned short* __restrict__ endD,
                                                 unsigned short* __restrict__ Eb) {
    const int tid = threadIdx.x;

    if (blockIdx.x >= NPREP) {
        // ================= GEMM branch =================
        // B-operand (Wc) staged per-kc as transposed bf16 in LDS: one
        // ds_read_b128 per (kc,nt) replaces 8 scalar global loads + 8 f2bf.
        // WcT[col][k'] rows are 64 B -> b128 read bank-starts 16*(mc&1)+4q:
        // 8 uniform groups of 8 lanes = balanced (no conflict overhead).
        __shared__ __align__(16) unsigned short WcT[DIM * 32];   // 8 KB

        const int lane = tid & 63, w = tid >> 6;
        const int q = lane >> 4, mc = lane & 15;
        const int rowBase = (blockIdx.x - NPREP) * 64;
        const int arow = min(rowBase + w * 16 + mc, VOCAB - 1);   // clamp, no OOB

        f32x4 acc[8];
        #pragma unroll
        for (int nt = 0; nt < 8; ++nt) acc[nt] = (f32x4){0.f, 0.f, 0.f, 0.f};

        const int kk = tid >> 3;           // 0..31 : k within stage
        const int c0 = (tid & 7) * 16;     // col base, 16 cols per thread

        #pragma unroll
        for (int kc = 0; kc < 4; ++kc) {
            // ---- stage Wc[kc*32 .. kc*32+31][*] transposed to bf16 ----
            const float* wsrc = &Wc[(kc * 32 + kk) * DIM + c0];
            float wv[16];
            *(float4*)(wv + 0)  = *(const float4*)(wsrc + 0);
            *(float4*)(wv + 4)  = *(const float4*)(wsrc + 4);
            *(float4*)(wv + 8)  = *(const float4*)(wsrc + 8);
            *(float4*)(wv + 12) = *(const float4*)(wsrc + 12);
            __syncthreads();   // previous stage's readers done (loads in flight)
            #pragma unroll
            for (int i = 0; i < 16; ++i)
                WcT[(c0 + i) * 32 + kk] = f2bf(wv[i]);
            __syncthreads();

            // ---- A fragment from emb (unchanged path) ----
            const float* src = &emb[(long long)arow * DIM + kc * 32 + q * 8];
            float4 v0 = *(const float4*)src;
            float4 v1 = *(const float4*)(src + 4);
            unsigned short aw[8] = {f2bf(v0.x), f2bf(v0.y), f2bf(v0.z), f2bf(v0.w),
                                    f2bf(v1.x), f2bf(v1.y), f2bf(v1.z), f2bf(v1.w)};
            bf16x8 a = *(bf16x8*)aw;

            #pragma unroll
            for (int nt = 0; nt < 8; ++nt) {
                bf16x8 bfr = *(bf16x8*)&WcT[(nt * 16 + mc) * 32 + q * 8];
                acc[nt] = __builtin_amdgcn_mfma_f32_16x16x32_bf16(a, bfr, acc[nt], 0, 0, 0);
            }
        }

        #pragma unroll
        for (int nt = 0; nt < 8; ++nt) {
            float bcv = bc[nt * 16 + mc];
            #pragma unroll
            for (int r = 0; r < 4; ++r) {
                int grow = rowBase + w * 16 + q * 4 + r;
                if (grow < VOCAB)
                    Eb[(long long)grow * DIM + nt * 16 + mc] = f2bf(acc[nt][r] + bcv);
            }
        }
        return;
    }

    // ================= PREP branch =================
    // Sibling offsets now via LDS atomicAdd (arbitrary-but-consistent sibling
    // order -> still a valid Euler tour; subtree sums are order-independent).
    // This deletes the former O(N^2) sibling-prefix loop (~500 serial iters
    // per thread), the dominant VALU cost of this branch.
    __shared__ unsigned short parL[NPB];
    __shared__ unsigned short depL[NPB];
    __shared__ int   tokL[NPB];
    __shared__ int   sizeL[NPB];
    __shared__ int   childCur[NPB];
    __shared__ unsigned short sibp[NPB];
    __shared__ unsigned short tinL[NPB];
    __shared__ unsigned short bucket[NPB];
    __shared__ int hist[MAXD + 1], off[MAXD + 1], cur[MAXD + 1];
    __shared__ int tmpTok[NPB];
    __shared__ unsigned short tmpEnd[NPB];
    __shared__ int sdmax;

    const int b = blockIdx.x;
    const long long base = (long long)b * NPB;

    if (tid <= MAXD) hist[tid] = 0;
    __syncthreads();
    for (int n = tid; n < NPB; n += 256) {
        int d = depth[base + n];
        depL[n]  = (unsigned short)d;
        parL[n]  = (unsigned short)(n == 0 ? 0 : (int)(parent[base + n] - base));
        tokL[n]  = tokens[base + n];
        sizeL[n] = 1;
        childCur[n] = 0;
        if (n > 0) atomicAdd(&hist[d], 1);
    }
    __syncthreads();

    if (tid < 64) {
        int h = (tid >= 1 && tid <= MAXD) ? hist[tid] : 0;
        int x = h;
        #pragma unroll
        for (int o = 1; o < 64; o <<= 1) { int y = __shfl_up(x, o, 64); if (tid >= o) x += y; }
        if (tid >= 1 && tid <= MAXD) { off[tid] = x - h; cur[tid] = x - h; }
        int dm = (h > 0) ? tid : 0;
        #pragma unroll
        for (int o = 32; o; o >>= 1) dm = max(dm, __shfl_down(dm, o));
        if (tid == 0) sdmax = dm;
    }
    __syncthreads();

    for (int n = 1 + tid; n < NPB; n += 256)
        bucket[atomicAdd(&cur[depL[n]], 1)] = (unsigned short)n;
    __syncthreads();
    const int dmax = sdmax;

    // bottom-up subtree sizes (depth-ordered, atomics within a level)
    for (int d = dmax; d >= 1; --d) {
        int c = hist[d], o = off[d];
        for (int i = tid; i < c; i += 256) {
            int n = bucket[o + i];
            atomicAdd(&sizeL[parL[n]], sizeL[n]);
        }
        __syncthreads();
    }

    // sibling offsets: exclusive prefix of sizes in atomic arrival order
    for (int n = 1 + tid; n < NPB; n += 256)
        sibp[n] = (unsigned short)atomicAdd(&childCur[parL[n]], sizeL[n]);
    if (tid == 0) tinL[0] = 0;
    __syncthreads();

    // top-down Euler (pre-order) positions
    for (int d = 1; d <= dmax; ++d) {
        int c = hist[d], o = off[d];
        for (int i = tid; i < c; i += 256) {
            int n = bucket[o + i];
            tinL[n] = (unsigned short)((int)tinL[parL[n]] + 1 + (int)sibp[n]);
        }
        __syncthreads();
    }

    for (int n = tid; n < NPB; n += 256) {
        int t = tinL[n];
        tmpTok[t] = tokL[n];
        tmpEnd[t] = (unsigned short)(t + sizeL[n] - 1);
    }
    __syncthreads();
    for (int t = tid; t < NPB; t += 256) {
        tokD[base + t] = tmpTok[t];
        endD[base + t] = tmpEnd[t];
    }
}

// ---------------- fused gather + prefix-scan + subtree-max ----------------
// bf16 IN-PLACE prefix storage: DMA lands bf16 values in Sbf; each thread
// consumes its own 32 elements into f32 registers (x[32]), writes back
// bf16(prefix) to the SAME slots (no cross-thread hazard), extract reads
// bf16 hi. LDS: 36 KB -> 4 blocks/CU (32-wave cap).
__global__ __launch_bounds__(512, 4) void scan_k(const int* __restrict__ tokD,
                                                 const unsigned short* __restrict__ endD,
                                                 const unsigned short* __restrict__ Eb,
                                                 float* __restrict__ out) {
    const int b = blockIdx.x & 511, s = blockIdx.x >> 9, tid = threadIdx.x;
    const long long base = (long long)b * NPB;
    __shared__ unsigned short Sbf[NPB * 32];  // 32000 B: values, then prefix (bf16)
    __shared__ unsigned short endL[NPB];      // 1000 B
    __shared__ float partials[16 * 32];       // 2048 B
    __shared__ float wmax[8 * 32];            // 1024 B

    // DMA gather first: node n = (tid>>2)+u*128, chunk q = tid&3.
    #pragma unroll
    for (int u = 0; u < 4; ++u) {
        int n = (tid >> 2) + u * 128;
        if (n < NPB) {
            int tok = tokD[base + n];         // coalesced: 16 consecutive ints/wave
            const unsigned short* g = &Eb[(long long)tok * DIM + s * 32 + (tid & 3) * 8];
            __builtin_amdgcn_global_load_lds(
                (const __attribute__((address_space(1))) void*)g,
                (__attribute__((address_space(3))) void*)&Sbf[n * 32 + (tid & 3) * 8],
                16, 0, 0);
        }
    }
    // overlap with DMA flight
    if (tid < NPB) endL[tid] = endD[base + tid];
    __syncthreads();

    const int j = tid & 31, c = tid >> 5;
    float x[32];
    {   // consume own chunk: bf16 -> f32 running sum in registers
        float run = 0.f;
        #pragma unroll
        for (int k = 0; k < 32; ++k) {
            int t = c * 32 + k;
            float v = (t < NPB)
                ? __uint_as_float((unsigned)Sbf[t * 32 + j] << 16) : 0.f;
            run += v; x[k] = run;
        }
        partials[c * 32 + j] = run;
    }
    __syncthreads();
    float off = 0.f;
    for (int cc = 0; cc < c; ++cc) off += partials[cc * 32 + j];
    #pragma unroll
    for (int k = 0; k < 32; ++k) {   // write back bf16 prefix to OWN slots
        int t = c * 32 + k;
        x[k] += off;
        if (t < NPB) Sbf[t * 32 + j] = f2bf(x[k]);
    }
    __syncthreads();

    // extract: lo from registers (full f32), hi from bf16 prefix
    float m = -INFINITY;
    #pragma unroll
    for (int k = 0; k < 32; ++k) {
        int t = c * 32 + k;
        if (t < NPB) {
            float hi = __uint_as_float((unsigned)Sbf[(int)endL[t] * 32 + j] << 16);
            float lo = (k > 0) ? x[k - 1] : off;
            m = fmaxf(m, hi - lo);
        }
    }
    m = fmaxf(m, __shfl_down(m, 32));
    if ((tid & 63) < 32) wmax[(tid >> 6) * 32 + j] = m;
    __syncthreads();
    if (tid < 32) {
        float mm = wmax[tid];
        #pragma unroll
        for (int w = 1; w < 8; ++w) mm = fmaxf(mm, wmax[w * 32 + tid]);
        out[b * DIM + s * 32 + tid] = fmaxf(mm, 0.0f);
    }
}

extern "C" void kernel_launch(void* const* d_in, const int* in_sizes, int n_in,
                              void* d_out, int out_size, void* d_ws, size_t ws_size,
                              hipStream_t stream) {
    const int*   tokens = (const int*)d_in[0];
    const int*   parent = (const int*)d_in[1];
    const int*   depth  = (const int*)d_in[2];
    // d_in[3] = node2batch (unused: node2batch[n] == n / 500 by construction)
    const float* emb    = (const float*)d_in[4];
    const float* Wc     = (const float*)d_in[5];
    const float* bc     = (const float*)d_in[6];
    float*       out    = (float*)d_out;

    unsigned short* Eb   = (unsigned short*)d_ws;                   // 12.8 MB bf16
    int*            tokD = (int*)(Eb + (long long)VOCAB * DIM);     // 1 MB
    unsigned short* endD = (unsigned short*)(tokD + B_BATCH * NPB); // 0.5 MB

    prep_gemm<<<NPREP + NGEMM, 256, 0, stream>>>(tokens, parent, depth,
                                                 emb, Wc, bc, tokD, endD, Eb);
    scan_k<<<B_BATCH * 4, 512, 0, stream>>>(tokD, endD, Eb, out);
}

// Round 2
// 124.563 us; speedup vs baseline: 1.1670x; 1.0541x over previous
//
#include <hip/hip_runtime.h>
#include <hip/hip_bf16.h>

#define B_BATCH 512
#define NPB     500
#define DIM     128
#define VOCAB   50000
#define MAXD    40
#define NPREP   512
#define NGEMM   ((VOCAB + 63) / 64)   // 782

typedef short bf16x8 __attribute__((ext_vector_type(8)));
typedef float f32x4  __attribute__((ext_vector_type(4)));

__device__ __forceinline__ unsigned short f2bf(float x) {
    unsigned u = __float_as_uint(x);
    return (unsigned short)((u + 0x7fffu + ((u >> 16) & 1u)) >> 16);   // RTNE
}

// ---------- fused prep (blocks 0..511) + MFMA gemm (blocks 512..1293) ----------
__global__ __launch_bounds__(256) void prep_gemm(const int* __restrict__ tokens,
                                                 const int* __restrict__ parent,
                                                 const int* __restrict__ depth,
                                                 const float* __restrict__ emb,
                                                 const float* __restrict__ Wc,
                                                 const float* __restrict__ bc,
                                                 int* __restrict__ tokD,
                                                 unsigned short* __restrict__ endD,
                                                 unsigned short* __restrict__ Eb) {
    const int tid = threadIdx.x;

    if (blockIdx.x >= NPREP) {
        // ================= GEMM branch =================
        __shared__ __align__(16) unsigned short WcT[DIM * 32];   // 8 KB

        const int lane = tid & 63, w = tid >> 6;
        const int q = lane >> 4, mc = lane & 15;
        const int rowBase = (blockIdx.x - NPREP) * 64;
        const int arow = min(rowBase + w * 16 + mc, VOCAB - 1);   // clamp, no OOB

        f32x4 acc[8];
        #pragma unroll
        for (int nt = 0; nt < 8; ++nt) acc[nt] = (f32x4){0.f, 0.f, 0.f, 0.f};

        const int kk = tid >> 3;           // 0..31 : k within stage
        const int c0 = (tid & 7) * 16;     // col base, 16 cols per thread

        #pragma unroll
        for (int kc = 0; kc < 4; ++kc) {
            // ---- stage Wc[kc*32 .. kc*32+31][*] transposed to bf16 ----
            const float* wsrc = &Wc[(kc * 32 + kk) * DIM + c0];
            float wv[16];
            *(float4*)(wv + 0)  = *(const float4*)(wsrc + 0);
            *(float4*)(wv + 4)  = *(const float4*)(wsrc + 4);
            *(float4*)(wv + 8)  = *(const float4*)(wsrc + 8);
            *(float4*)(wv + 12) = *(const float4*)(wsrc + 12);
            __syncthreads();   // previous stage's readers done (loads in flight)
            #pragma unroll
            for (int i = 0; i < 16; ++i)
                WcT[(c0 + i) * 32 + kk] = f2bf(wv[i]);
            __syncthreads();

            // ---- A fragment from emb ----
            const float* src = &emb[(long long)arow * DIM + kc * 32 + q * 8];
            float4 v0 = *(const float4*)src;
            float4 v1 = *(const float4*)(src + 4);
            unsigned short aw[8] = {f2bf(v0.x), f2bf(v0.y), f2bf(v0.z), f2bf(v0.w),
                                    f2bf(v1.x), f2bf(v1.y), f2bf(v1.z), f2bf(v1.w)};
            bf16x8 a = *(bf16x8*)aw;

            #pragma unroll
            for (int nt = 0; nt < 8; ++nt) {
                bf16x8 bfr = *(bf16x8*)&WcT[(nt * 16 + mc) * 32 + q * 8];
                acc[nt] = __builtin_amdgcn_mfma_f32_16x16x32_bf16(a, bfr, acc[nt], 0, 0, 0);
            }
        }

        #pragma unroll
        for (int nt = 0; nt < 8; ++nt) {
            float bcv = bc[nt * 16 + mc];
            #pragma unroll
            for (int r = 0; r < 4; ++r) {
                int grow = rowBase + w * 16 + q * 4 + r;
                if (grow < VOCAB)
                    Eb[(long long)grow * DIM + nt * 16 + mc] = f2bf(acc[nt][r] + bcv);
            }
        }
        return;
    }

    // ================= PREP branch =================
    __shared__ unsigned short parL[NPB];
    __shared__ unsigned short depL[NPB];
    __shared__ int   tokL[NPB];
    __shared__ int   sizeL[NPB];
    __shared__ int   childCur[NPB];
    __shared__ unsigned short sibp[NPB];
    __shared__ unsigned short tinL[NPB];
    __shared__ unsigned short bucket[NPB];
    __shared__ int hist[MAXD + 1], off[MAXD + 1], cur[MAXD + 1];
    __shared__ int tmpTok[NPB];
    __shared__ unsigned short tmpEnd[NPB];
    __shared__ int sdmax;

    const int b = blockIdx.x;
    const long long base = (long long)b * NPB;

    if (tid <= MAXD) hist[tid] = 0;
    __syncthreads();
    for (int n = tid; n < NPB; n += 256) {
        int d = depth[base + n];
        depL[n]  = (unsigned short)d;
        parL[n]  = (unsigned short)(n == 0 ? 0 : (int)(parent[base + n] - base));
        tokL[n]  = tokens[base + n];
        sizeL[n] = 1;
        childCur[n] = 0;
        if (n > 0) atomicAdd(&hist[d], 1);
    }
    __syncthreads();

    if (tid < 64) {
        int h = (tid >= 1 && tid <= MAXD) ? hist[tid] : 0;
        int x = h;
        #pragma unroll
        for (int o = 1; o < 64; o <<= 1) { int y = __shfl_up(x, o, 64); if (tid >= o) x += y; }
        if (tid >= 1 && tid <= MAXD) { off[tid] = x - h; cur[tid] = x - h; }
        int dm = (h > 0) ? tid : 0;
        #pragma unroll
        for (int o = 32; o; o >>= 1) dm = max(dm, __shfl_down(dm, o));
        if (tid == 0) sdmax = dm;
    }
    __syncthreads();

    for (int n = 1 + tid; n < NPB; n += 256)
        bucket[atomicAdd(&cur[depL[n]], 1)] = (unsigned short)n;
    __syncthreads();
    const int dmax = sdmax;

    // bottom-up subtree sizes (depth-ordered, atomics within a level)
    for (int d = dmax; d >= 1; --d) {
        int c = hist[d], o = off[d];
        for (int i = tid; i < c; i += 256) {
            int n = bucket[o + i];
            atomicAdd(&sizeL[parL[n]], sizeL[n]);
        }
        __syncthreads();
    }

    // sibling offsets: exclusive prefix of sizes in atomic arrival order
    for (int n = 1 + tid; n < NPB; n += 256)
        sibp[n] = (unsigned short)atomicAdd(&childCur[parL[n]], sizeL[n]);
    if (tid == 0) tinL[0] = 0;
    __syncthreads();

    // top-down Euler (pre-order) positions
    for (int d = 1; d <= dmax; ++d) {
        int c = hist[d], o = off[d];
        for (int i = tid; i < c; i += 256) {
            int n = bucket[o + i];
            tinL[n] = (unsigned short)((int)tinL[parL[n]] + 1 + (int)sibp[n]);
        }
        __syncthreads();
    }

    for (int n = tid; n < NPB; n += 256) {
        int t = tinL[n];
        tmpTok[t] = tokL[n];
        tmpEnd[t] = (unsigned short)(t + sizeL[n] - 1);
    }
    __syncthreads();
    for (int t = tid; t < NPB; t += 256) {
        tokD[base + t] = tmpTok[t];
        endD[base + t] = tmpEnd[t];
    }
}

// ---------------- fused gather + prefix-scan + subtree-max ----------------
// MERGED s-slice pairs: one block = 64 channels (sp*64..sp*64+63), 1024 thr.
// Gather now fetches a FULL 128 B cache line per node exactly once machine-
// wide (8 lanes x 16 B contiguous), vs. two 64 B half-line fetches from two
// different blocks/XCDs before -> scattered L3 line traffic and VMEM request
// count both halve. Wave == one scan chunk (c = wave id, j = lane), so the
// intra-wave shfl max-reduce disappears. LDS 73 KB -> 2 blocks/CU (32 w/CU).
__global__ __launch_bounds__(1024) void scan_k(const int* __restrict__ tokD,
                                               const unsigned short* __restrict__ endD,
                                               const unsigned short* __restrict__ Eb,
                                               float* __restrict__ out) {
    const int b = blockIdx.x & 511, sp = blockIdx.x >> 9, tid = threadIdx.x;
    const long long base = (long long)b * NPB;
    __shared__ unsigned short Sbf[NPB * 64];   // 64000 B: values, then prefix (bf16)
    __shared__ unsigned short endL[NPB];       // 1000 B
    __shared__ float partials[16 * 64];        // 4096 B
    __shared__ float wmax[16 * 64];            // 4096 B

    // DMA gather: node n = (tid>>3)+u*128, chunk q = tid&7 (8 lanes = 128 B/row).
    #pragma unroll
    for (int u = 0; u < 4; ++u) {
        int n = (tid >> 3) + u * 128;
        if (n < NPB) {
            int tok = tokD[base + n];          // 8 consecutive lanes share one int
            const unsigned short* g = &Eb[(long long)tok * DIM + sp * 64 + (tid & 7) * 8];
            __builtin_amdgcn_global_load_lds(
                (const __attribute__((address_space(1))) void*)g,
                (__attribute__((address_space(3))) void*)&Sbf[n * 64 + (tid & 7) * 8],
                16, 0, 0);
        }
    }
    // overlap with DMA flight
    if (tid < NPB) endL[tid] = endD[base + tid];
    __syncthreads();

    const int j = tid & 63, c = tid >> 6;      // wave == chunk c, lane == channel j
    float x[32];
    {   // consume own chunk: bf16 -> f32 running sum in registers
        float run = 0.f;
        #pragma unroll
        for (int k = 0; k < 32; ++k) {
            int t = c * 32 + k;
            float v = (t < NPB)
                ? __uint_as_float((unsigned)Sbf[t * 64 + j] << 16) : 0.f;
            run += v; x[k] = run;
        }
        partials[c * 64 + j] = run;
    }
    __syncthreads();
    float off = 0.f;
    for (int cc = 0; cc < c; ++cc) off += partials[cc * 64 + j];
    #pragma unroll
    for (int k = 0; k < 32; ++k) {   // write back bf16 prefix to OWN slots
        int t = c * 32 + k;
        x[k] += off;
        if (t < NPB) Sbf[t * 64 + j] = f2bf(x[k]);
    }
    __syncthreads();

    // extract: lo from registers (full f32), hi from bf16 prefix
    float m = -INFINITY;
    #pragma unroll
    for (int k = 0; k < 32; ++k) {
        int t = c * 32 + k;
        if (t < NPB) {
            float hi = __uint_as_float((unsigned)Sbf[(int)endL[t] * 64 + j] << 16);
            float lo = (k > 0) ? x[k - 1] : off;
            m = fmaxf(m, hi - lo);
        }
    }
    wmax[c * 64 + j] = m;                      // wave-uniform c: no shfl needed
    __syncthreads();
    if (tid < 64) {
        float mm = wmax[tid];
        #pragma unroll
        for (int w = 1; w < 16; ++w) mm = fmaxf(mm, wmax[w * 64 + tid]);
        out[b * DIM + sp * 64 + tid] = fmaxf(mm, 0.0f);
    }
}

extern "C" void kernel_launch(void* const* d_in, const int* in_sizes, int n_in,
                              void* d_out, int out_size, void* d_ws, size_t ws_size,
                              hipStream_t stream) {
    const int*   tokens = (const int*)d_in[0];
    const int*   parent = (const int*)d_in[1];
    const int*   depth  = (const int*)d_in[2];
    // d_in[3] = node2batch (unused: node2batch[n] == n / 500 by construction)
    const float* emb    = (const float*)d_in[4];
    const float* Wc     = (const float*)d_in[5];
    const float* bc     = (const float*)d_in[6];
    float*       out    = (float*)d_out;

    unsigned short* Eb   = (unsigned short*)d_ws;                   // 12.8 MB bf16
    int*            tokD = (int*)(Eb + (long long)VOCAB * DIM);     // 1 MB
    unsigned short* endD = (unsigned short*)(tokD + B_BATCH * NPB); // 0.5 MB

    prep_gemm<<<NPREP + NGEMM, 256, 0, stream>>>(tokens, parent, depth,
                                                 emb, Wc, bc, tokD, endD, Eb);
    scan_k<<<B_BATCH * 2, 1024, 0, stream>>>(tokD, endD, Eb, out);
}